// Round 1
// baseline (65.866 us; speedup 1.0000x reference)
//
#include <hip/hip_runtime.h>

// Problem constants (from reference): B=8, L=4096, D=1024, MAX_CHUNKS=128
#define B_DIM 8
#define L_DIM 4096
#define D_DIM 1024
#define MAXC 128

// ---------------------------------------------------------------------------
// Kernel A: per batch, find boundary positions (boundaries > 0.5) in order.
// 256 threads/block, each thread owns 16 contiguous elements of the row.
// Block-wide Hillis-Steele scan gives each thread its write offset.
// ---------------------------------------------------------------------------
__global__ void find_boundaries_kernel(const float* __restrict__ bnd,
                                       int* __restrict__ pos,   // [B][L]
                                       int* __restrict__ nseg)  // [B]
{
    const int b = blockIdx.x;
    const int t = threadIdx.x;           // 0..255
    const float* p = bnd + (size_t)b * L_DIM;
    const int base = t * 16;

    unsigned m = 0u;
#pragma unroll
    for (int j = 0; j < 16; ++j) {
        m |= (p[base + j] > 0.5f) ? (1u << j) : 0u;
    }
    int cnt = __popc(m);

    __shared__ int s[256];
    s[t] = cnt;
    __syncthreads();
    // inclusive scan (Hillis-Steele)
    for (int off = 1; off < 256; off <<= 1) {
        int v = (t >= off) ? s[t - off] : 0;
        __syncthreads();
        s[t] += v;
        __syncthreads();
    }
    int excl = s[t] - cnt;
    int* op = pos + (size_t)b * L_DIM;
    int idx = excl;
#pragma unroll
    for (int j = 0; j < 16; ++j) {
        if (m & (1u << j)) op[idx++] = base + j;
    }
    if (t == 255) nseg[b] = s[255];
}

// ---------------------------------------------------------------------------
// Kernel B: one block per (batch, chunk). 256 threads, each owns a float4
// column slice (256*4 = 1024 = D). Loop over the chunk's rows, accumulate,
// write mean. Empty chunks write zeros / count 0.
// Counts are written as float values at the tail of the flat fp32 output.
// ---------------------------------------------------------------------------
__global__ void pool_chunks_kernel(const float* __restrict__ x,
                                   const int* __restrict__ pos,
                                   const int* __restrict__ nseg,
                                   float* __restrict__ out_means,  // [B][MAXC][D]
                                   float* __restrict__ out_cnts)   // [B][MAXC]
{
    const int bc = blockIdx.x;          // 0 .. B*MAXC-1
    const int b  = bc >> 7;             // / MAXC
    const int c  = bc & (MAXC - 1);
    const int t  = threadIdx.x;         // 0..255

    const int n = nseg[b];

    float4 acc = make_float4(0.f, 0.f, 0.f, 0.f);
    int cnt = 0;

    if (c < n) {
        const int* pp = pos + (size_t)b * L_DIM;
        const int start = pp[c];
        const int end   = (c + 1 < n) ? pp[c + 1] : L_DIM;
        cnt = end - start;

        const float* xp = x + ((size_t)b * L_DIM + start) * D_DIM + t * 4;
        for (int r = 0; r < cnt; ++r) {
            float4 v = *reinterpret_cast<const float4*>(xp + (size_t)r * D_DIM);
            acc.x += v.x; acc.y += v.y; acc.z += v.z; acc.w += v.w;
        }
        const float inv = 1.0f / (float)cnt;
        acc.x *= inv; acc.y *= inv; acc.z *= inv; acc.w *= inv;
    }

    float4* op = reinterpret_cast<float4*>(out_means + (size_t)bc * D_DIM) + t;
    *op = acc;
    if (t == 0) out_cnts[bc] = (float)cnt;
}

extern "C" void kernel_launch(void* const* d_in, const int* in_sizes, int n_in,
                              void* d_out, int out_size, void* d_ws, size_t ws_size,
                              hipStream_t stream)
{
    const float* x   = (const float*)d_in[0];   // [B, L, D] fp32
    const float* bnd = (const float*)d_in[1];   // [B, L]    fp32

    float* out = (float*)d_out;
    float* out_means = out;                               // B*MAXC*D floats
    float* out_cnts  = out + (size_t)B_DIM * MAXC * D_DIM; // B*MAXC floats

    // workspace layout: pos[B][L] ints, then nseg[B] ints
    int* pos  = (int*)d_ws;
    int* nseg = pos + (size_t)B_DIM * L_DIM;

    find_boundaries_kernel<<<B_DIM, 256, 0, stream>>>(bnd, pos, nseg);
    pool_chunks_kernel<<<B_DIM * MAXC, 256, 0, stream>>>(x, pos, nseg,
                                                         out_means, out_cnts);
}

// Round 2
// 39.637 us; speedup vs baseline: 1.6617x; 1.6617x over previous
//
#include <hip/hip_runtime.h>

// Problem constants (from reference): B=8, L=4096, D=1024, MAX_CHUNKS=128
#define B_DIM 8
#define L_DIM 4096
#define D_DIM 1024
#define MAXC 128

__device__ __forceinline__ void f4add(float4& a, const float4& v) {
    a.x += v.x; a.y += v.y; a.z += v.z; a.w += v.w;
}

// ---------------------------------------------------------------------------
// Kernel A: per batch, find boundary positions (boundaries > 0.5) in order.
// 256 threads/block, each thread owns 16 contiguous elements of the row.
// Block-wide Hillis-Steele scan gives each thread its write offset.
// ---------------------------------------------------------------------------
__global__ void find_boundaries_kernel(const float* __restrict__ bnd,
                                       int* __restrict__ pos,   // [B][L]
                                       int* __restrict__ nseg)  // [B]
{
    const int b = blockIdx.x;
    const int t = threadIdx.x;           // 0..255
    const float* p = bnd + (size_t)b * L_DIM;
    const int base = t * 16;

    unsigned m = 0u;
#pragma unroll
    for (int j = 0; j < 16; ++j) {
        m |= (p[base + j] > 0.5f) ? (1u << j) : 0u;
    }
    int cnt = __popc(m);

    __shared__ int s[256];
    s[t] = cnt;
    __syncthreads();
    // inclusive scan (Hillis-Steele)
    for (int off = 1; off < 256; off <<= 1) {
        int v = (t >= off) ? s[t - off] : 0;
        __syncthreads();
        s[t] += v;
        __syncthreads();
    }
    int excl = s[t] - cnt;
    int* op = pos + (size_t)b * L_DIM;
    int idx = excl;
#pragma unroll
    for (int j = 0; j < 16; ++j) {
        if (m & (1u << j)) op[idx++] = base + j;
    }
    if (t == 255) nseg[b] = s[255];
}

// ---------------------------------------------------------------------------
// Kernel B: one block per (batch, chunk). 256 threads, each owns a float4
// column slice. Rows unrolled by 8 with 8 independent accumulators so 8
// global_load_dwordx4 are in flight per wave (breaks the dependent
// load->wait->add chain that made the long-chunk tail latency-bound).
// ---------------------------------------------------------------------------
__global__ void pool_chunks_kernel(const float* __restrict__ x,
                                   const int* __restrict__ pos,
                                   const int* __restrict__ nseg,
                                   float* __restrict__ out_means,  // [B][MAXC][D]
                                   float* __restrict__ out_cnts)   // [B][MAXC]
{
    const int bc = blockIdx.x;          // 0 .. B*MAXC-1
    const int b  = bc >> 7;             // / MAXC
    const int c  = bc & (MAXC - 1);
    const int t  = threadIdx.x;         // 0..255

    const int n = nseg[b];

    float4 acc = make_float4(0.f, 0.f, 0.f, 0.f);
    int cnt = 0;

    if (c < n) {
        const int* pp = pos + (size_t)b * L_DIM;
        const int start = pp[c];
        const int end   = (c + 1 < n) ? pp[c + 1] : L_DIM;
        cnt = end - start;

        const float* xp = x + ((size_t)b * L_DIM + start) * D_DIM + t * 4;

        float4 a0 = make_float4(0.f,0.f,0.f,0.f), a1 = a0, a2 = a0, a3 = a0;
        float4 a4 = a0, a5 = a0, a6 = a0, a7 = a0;

        int r = 0;
        for (; r + 8 <= cnt; r += 8) {
            const float4* base = reinterpret_cast<const float4*>(xp + (size_t)r * D_DIM);
            float4 v0 = base[0 * (D_DIM / 4)];
            float4 v1 = base[1 * (D_DIM / 4)];
            float4 v2 = base[2 * (D_DIM / 4)];
            float4 v3 = base[3 * (D_DIM / 4)];
            float4 v4 = base[4 * (D_DIM / 4)];
            float4 v5 = base[5 * (D_DIM / 4)];
            float4 v6 = base[6 * (D_DIM / 4)];
            float4 v7 = base[7 * (D_DIM / 4)];
            f4add(a0, v0); f4add(a1, v1); f4add(a2, v2); f4add(a3, v3);
            f4add(a4, v4); f4add(a5, v5); f4add(a6, v6); f4add(a7, v7);
        }
        for (; r < cnt; ++r) {
            float4 v = *reinterpret_cast<const float4*>(xp + (size_t)r * D_DIM);
            f4add(a0, v);
        }
        f4add(a0, a1); f4add(a2, a3); f4add(a4, a5); f4add(a6, a7);
        f4add(a0, a2); f4add(a4, a6);
        f4add(a0, a4);
        acc = a0;

        const float inv = 1.0f / (float)cnt;
        acc.x *= inv; acc.y *= inv; acc.z *= inv; acc.w *= inv;
    }

    float4* op = reinterpret_cast<float4*>(out_means + (size_t)bc * D_DIM) + t;
    *op = acc;
    if (t == 0) out_cnts[bc] = (float)cnt;
}

extern "C" void kernel_launch(void* const* d_in, const int* in_sizes, int n_in,
                              void* d_out, int out_size, void* d_ws, size_t ws_size,
                              hipStream_t stream)
{
    const float* x   = (const float*)d_in[0];   // [B, L, D] fp32
    const float* bnd = (const float*)d_in[1];   // [B, L]    fp32

    float* out = (float*)d_out;
    float* out_means = out;                               // B*MAXC*D floats
    float* out_cnts  = out + (size_t)B_DIM * MAXC * D_DIM; // B*MAXC floats

    // workspace layout: pos[B][L] ints, then nseg[B] ints
    int* pos  = (int*)d_ws;
    int* nseg = pos + (size_t)B_DIM * L_DIM;

    find_boundaries_kernel<<<B_DIM, 256, 0, stream>>>(bnd, pos, nseg);
    pool_chunks_kernel<<<B_DIM * MAXC, 256, 0, stream>>>(x, pos, nseg,
                                                         out_means, out_cnts);
}